// Round 3
// baseline (337.029 us; speedup 1.0000x reference)
//
#include <hip/hip_runtime.h>
#include <hip/hip_bf16.h>

#define N_FEAT 8192
#define D_MODEL 256
#define HEADS 4
#define CELLS 32
#define BATCH 4096
#define HC 128          // HEADS*CELLS
#define NT 32           // n-rows per reps block
#define DC 64           // d-chunk
#define KSPLIT 16
#define KCH (N_FEAT / KSPLIT)   // 512

typedef __attribute__((ext_vector_type(8))) short bf16x8;
typedef __attribute__((ext_vector_type(4))) float f32x4;

__device__ __forceinline__ unsigned short f32_to_bf16(float f) {
    union { float f; unsigned u; } v; v.f = f;
    unsigned r = v.u + 0x7fffu + ((v.u >> 16) & 1u);
    return (unsigned short)(r >> 16);
}

__device__ __forceinline__ float bf16_to_f32(unsigned short h) {
    union { unsigned u; float f; } v; v.u = ((unsigned)h) << 16;
    return v.f;
}

// direct global->LDS DMA, 16B per lane; global src is PER-LANE, LDS dest is
// wave-uniform base (+ lane*16 added by HW)
__device__ __forceinline__ void gload16(const void* gsrc, void* ldst) {
    __builtin_amdgcn_global_load_lds(
        (const __attribute__((address_space(1))) unsigned int*)gsrc,
        (__attribute__((address_space(3))) unsigned int*)ldst, 16, 0, 0);
}

// ---------------------------------------------------------------------------
// Packed tile layouts (all intermediates are fragment-native):
//   repsT  : [n_blk(2)][k_step(256)][kq(4)][row(128)][8] bf16   (gemm1 B)
//   reps_bf: [n_blk(64)][ks2(8)][kq(4)][row(128)][8] bf16       (gemm2 B)
//   hb/hp  : [m_blk(32)][ks2(8)][kq(4)][row(128)][8] bf16       (gemm2 A)
// Each (blk, step) tile is 8 KB contiguous -> linear DMA; fragment read
// addr = kq*1024 + row*8 shorts -> 16 consecutive 16B slots per l16 group
// -> conflict-free.
// ---------------------------------------------------------------------------

// ---------------------------------------------------------------------------
// Stage 1 (fused): tropical scores -> top-2 -> sigmoid blend -> packed writes
// ---------------------------------------------------------------------------
__global__ __launch_bounds__(256) void reps_kernel(
    const float* __restrict__ proj, const float* __restrict__ rw,
    const float* __restrict__ rb, const float* __restrict__ cb,
    unsigned short* __restrict__ reps_bf, unsigned short* __restrict__ repsT)
{
    __shared__ float latS[NT][DC + 4];
    __shared__ float wS[HC][DC + 4];
    __shared__ float sc[NT][HC + 4];
    __shared__ float T[NT][257];
    __shared__ float gateS[NT][HEADS];
    __shared__ int   widxS[NT][HEADS], ridxS[NT][HEADS];

    const int t = threadIdx.x;
    const int nbase = blockIdx.x * NT;
    const int tx = t & 31, ty = t >> 5;
    const int hc0 = tx * 4, n0 = ty * 4;

    float acc[4][4];
    #pragma unroll
    for (int i = 0; i < 4; ++i)
        #pragma unroll
        for (int j = 0; j < 4; ++j)
            acc[i][j] = -3.4e38f;

    for (int dk = 0; dk < D_MODEL; dk += DC) {
        __syncthreads();
        {
            int f = t;
            #pragma unroll
            for (int i = 0; i < 2; ++i, f += 256) {
                const int row = f >> 4, c4 = f & 15;
                float4 v = *(const float4*)&proj[(long)(nbase + row) * D_MODEL + dk + c4 * 4];
                *(float4*)&latS[row][c4 * 4] = v;
            }
        }
        {
            int f = t;
            #pragma unroll
            for (int i = 0; i < 8; ++i, f += 256) {
                const int row = f >> 4, c4 = f & 15;
                float4 v = *(const float4*)&rw[(long)row * D_MODEL + dk + c4 * 4];
                *(float4*)&wS[row][c4 * 4] = v;
            }
        }
        __syncthreads();

        #pragma unroll 4
        for (int d = 0; d < DC; d += 4) {
            float4 la[4], wv[4];
            #pragma unroll
            for (int i = 0; i < 4; ++i) la[i] = *(const float4*)&latS[n0 + i][d];
            #pragma unroll
            for (int j = 0; j < 4; ++j) wv[j] = *(const float4*)&wS[hc0 + j][d];
            #pragma unroll
            for (int i = 0; i < 4; ++i)
                #pragma unroll
                for (int j = 0; j < 4; ++j) {
                    float m01 = fmaxf(la[i].x + wv[j].x, la[i].y + wv[j].y);
                    float m23 = fmaxf(la[i].z + wv[j].z, la[i].w + wv[j].w);
                    acc[i][j] = fmaxf(acc[i][j], fmaxf(m01, m23));
                }
        }
    }

    #pragma unroll
    for (int j = 0; j < 4; ++j) {
        const float rbv = rb[hc0 + j];
        #pragma unroll
        for (int i = 0; i < 4; ++i)
            sc[n0 + i][hc0 + j] = acc[i][j] + rbv;
    }
    __syncthreads();

    if (t < NT * HEADS) {
        const int n = t >> 2, h = t & 3;
        float v1 = -3.4e38f, v2 = -3.4e38f; int i1 = 0, i2 = 0;
        #pragma unroll
        for (int c = 0; c < CELLS; ++c) {
            float s = sc[n][h * CELLS + c];
            if (s > v1) { v2 = v1; i2 = i1; v1 = s; i1 = c; }
            else if (s > v2) { v2 = s; i2 = c; }
        }
        gateS[n][h] = 1.0f / (1.0f + __expf(-(v1 - v2)));
        widxS[n][h] = i1; ridxS[n][h] = i2;
    }
    __syncthreads();

    // blend; write reps_bf in gemm2-B packed layout; keep f32 row in T
    const long nblk2 = nbase >> 7;          // gemm2 n-block
    const int  rbase = nbase & 127;         // row128 base within that block
    #pragma unroll 4
    for (int r = 0; r < NT; ++r) {
        float val = proj[(long)(nbase + r) * D_MODEL + t];
        #pragma unroll
        for (int h = 0; h < HEADS; ++h) {
            const float g = gateS[r][h];
            const float wv = cb[(long)(h * CELLS + widxS[r][h]) * D_MODEL + t];
            const float rv = cb[(long)(h * CELLS + ridxS[r][h]) * D_MODEL + t];
            val += g * wv + (1.0f - g) * rv;   // CODE_SCALE = 1
        }
        // d = t: ks2 = t>>5, kq = (t>>3)&3, ko = t&7
        const long bidx = ((((nblk2 * 8 + (t >> 5)) * 4 + ((t >> 3) & 3)) * 128
                           + (rbase + r)) << 3) + (t & 7);
        reps_bf[bidx] = f32_to_bf16(val);
        T[r][t] = val;
    }
    __syncthreads();

    // pack repsT tiles for gemm1 B: this block covers one gemm1 k_step
    // thread t = d (0..255): n_blk = t>>7, row = t&127
    {
        const int ksA = nbase >> 5;     // gemm1 k-step index (global)
        const long tb = (((long)(t >> 7) * 256 + ksA) * 4);
        #pragma unroll
        for (int kq = 0; kq < 4; ++kq) {
            unsigned short tmp[8];
            #pragma unroll
            for (int ko = 0; ko < 8; ++ko)
                tmp[ko] = f32_to_bf16(T[kq * 8 + ko][t]);
            *(uint4*)&repsT[((tb + kq) * 128 + (t & 127)) << 3] = *(const uint4*)tmp;
        }
    }
}

// ---------------------------------------------------------------------------
// Stage 2: hidden_part[ks] = x[:, ks-chunk] @ reps[ks-chunk, :]  (bf16 out)
// 128x128 tile, 4 waves, 4x4 16x16x32 MFMA, K-split x16.
// B: linear 8KB DMA from packed repsT tiles. A: reg-staged (T14 split:
// loads issued before MFMA phase, cvt+ds_write after) into [kq][row][8].
// All LDS reads conflict-free. 32 KB LDS total.
// ---------------------------------------------------------------------------
__global__ __launch_bounds__(256) void gemm1_kernel(
    const float* __restrict__ x, const unsigned short* __restrict__ repsT,
    unsigned short* __restrict__ hidden_part)
{
    __shared__ unsigned short As[2][4096];   // [kq(4)][row(128)][8] bf16, 8KB
    __shared__ unsigned short Bs[2][4096];

    const int m0 = blockIdx.y * 128;
    const int nb = blockIdx.x;               // 0..1  (d-block of 128)
    const int ks = blockIdx.z;
    const int t = threadIdx.x;
    const int wave = t >> 6, lane = t & 63;
    const int wm = (wave >> 1) * 64, wn = (wave & 1) * 64;
    const int quad = lane >> 4, l16 = lane & 15;
    const int kbeg = ks * KCH;
    const int ks0 = kbeg >> 5;               // first global k-step
    const int nsteps = KCH / 32;             // 16

    // A staging geometry: row = t>>1, half h = t&1 (16 f32 = k-octets 2h, 2h+1)
    const int arow = t >> 1, ah = t & 1;
    const float* asrc = x + (long)(m0 + arow) * N_FEAT + ah * 16;
    const int aw0 = (ah * 2 + 0) * 1024 + arow * 8;   // ushort idx
    const int aw1 = (ah * 2 + 1) * 1024 + arow * 8;

    f32x4 acc[4][4];
    #pragma unroll
    for (int i = 0; i < 4; ++i)
        #pragma unroll
        for (int j = 0; j < 4; ++j)
            acc[i][j] = (f32x4){0.f, 0.f, 0.f, 0.f};

    // prologue: stage step 0
    {
        const char* src = (const char*)(repsT + ((long)(nb * 256 + ks0) << 12));
        char* dst = (char*)&Bs[0][0];
        #pragma unroll
        for (int i = 0; i < 2; ++i)
            gload16(src + wave * 1024 + i * 4096 + lane * 16,
                    dst + wave * 1024 + i * 4096);
        const float4* ap = (const float4*)(asrc + kbeg);
        float4 av0 = ap[0], av1 = ap[1], av2 = ap[2], av3 = ap[3];
        unsigned short tmp[16];
        float fv[16] = {av0.x, av0.y, av0.z, av0.w, av1.x, av1.y, av1.z, av1.w,
                        av2.x, av2.y, av2.z, av2.w, av3.x, av3.y, av3.z, av3.w};
        #pragma unroll
        for (int e = 0; e < 16; ++e) tmp[e] = f32_to_bf16(fv[e]);
        *(uint4*)&As[0][aw0] = *(const uint4*)tmp;
        *(uint4*)&As[0][aw1] = *(const uint4*)(tmp + 8);
    }
    __syncthreads();

    int cur = 0;
    #pragma unroll 1
    for (int s = 0; s < nsteps; ++s) {
        float4 av0, av1, av2, av3;
        const bool pf = (s + 1 < nsteps);
        if (pf) {
            // issue next B DMA + next A global loads (in flight across MFMAs)
            const char* src = (const char*)(repsT + ((long)(nb * 256 + ks0 + s + 1) << 12));
            char* dst = (char*)&Bs[cur ^ 1][0];
            #pragma unroll
            for (int i = 0; i < 2; ++i)
                gload16(src + wave * 1024 + i * 4096 + lane * 16,
                        dst + wave * 1024 + i * 4096);
            const float4* ap = (const float4*)(asrc + kbeg + (s + 1) * 32);
            av0 = ap[0]; av1 = ap[1]; av2 = ap[2]; av3 = ap[3];
        }

        // fragments (conflict-free: 16 consecutive 16B slots per read)
        bf16x8 af[4], bfr[4];
        #pragma unroll
        for (int i = 0; i < 4; ++i)
            af[i] = *(const bf16x8*)&As[cur][quad * 1024 + (wm + i * 16 + l16) * 8];
        #pragma unroll
        for (int j = 0; j < 4; ++j)
            bfr[j] = *(const bf16x8*)&Bs[cur][quad * 1024 + (wn + j * 16 + l16) * 8];

        #pragma unroll
        for (int i = 0; i < 4; ++i)
            #pragma unroll
            for (int j = 0; j < 4; ++j)
                acc[i][j] = __builtin_amdgcn_mfma_f32_16x16x32_bf16(
                    af[i], bfr[j], acc[i][j], 0, 0, 0);

        if (pf) {
            // vmcnt wait for A regs lands here, after the MFMA phase
            unsigned short tmp[16];
            float fv[16] = {av0.x, av0.y, av0.z, av0.w, av1.x, av1.y, av1.z, av1.w,
                            av2.x, av2.y, av2.z, av2.w, av3.x, av3.y, av3.z, av3.w};
            #pragma unroll
            for (int e = 0; e < 16; ++e) tmp[e] = f32_to_bf16(fv[e]);
            *(uint4*)&As[cur ^ 1][aw0] = *(const uint4*)tmp;
            *(uint4*)&As[cur ^ 1][aw1] = *(const uint4*)(tmp + 8);
        }
        __syncthreads();
        cur ^= 1;
    }

    // epilogue: write hp stripe in gemm2-A packed layout
    unsigned short* hp = hidden_part + (long)ks * (BATCH * D_MODEL);
    #pragma unroll
    for (int i = 0; i < 4; ++i)
        #pragma unroll
        for (int j = 0; j < 4; ++j) {
            const int d0 = nb * 128 + wn + j * 16;        // multiple of 16
            const int ks2 = d0 >> 5;                      // fixed across l16
            const int kq2 = ((d0 + l16) >> 3) & 3;
            const int ko  = l16 & 7;
            const long cb = ((long)blockIdx.y * 8 + ks2) * 4 + kq2;
            #pragma unroll
            for (int r = 0; r < 4; ++r) {
                const int row128 = wm + i * 16 + quad * 4 + r;
                hp[((cb * 128 + row128) << 3) + ko] = f32_to_bf16(acc[i][j][r]);
            }
        }
}

// ---------------------------------------------------------------------------
// Stage 2b: hb = bf16( sum of 16 bf16 K-split partials ) — layout-agnostic
// ---------------------------------------------------------------------------
__global__ __launch_bounds__(256) void reduce_kernel(
    const unsigned short* __restrict__ hp, unsigned short* __restrict__ hb)
{
    const int id = blockIdx.x * 256 + threadIdx.x;   // over 131072 uint4 (8 bf16)
    const int S = BATCH * D_MODEL / 8;
    const uint4* p = (const uint4*)hp;
    float s[8] = {0.f, 0.f, 0.f, 0.f, 0.f, 0.f, 0.f, 0.f};
    #pragma unroll
    for (int k = 0; k < KSPLIT; ++k) {
        uint4 v = p[(long)k * S + id];
        unsigned short e[8];
        *(uint4*)e = v;
        #pragma unroll
        for (int j = 0; j < 8; ++j) s[j] += bf16_to_f32(e[j]);
    }
    unsigned short o[8];
    #pragma unroll
    for (int j = 0; j < 8; ++j) o[j] = f32_to_bf16(s[j]);
    ((uint4*)hb)[id] = *(const uint4*)o;
}

// ---------------------------------------------------------------------------
// Stage 3: out = relu(hidden @ reps^T + bias)   M=4096 N=8192 K=256
// Both operands DMA'd linearly from packed tiles; conflict-free reads.
// ---------------------------------------------------------------------------
__global__ __launch_bounds__(256) void gemm2_kernel(
    const unsigned short* __restrict__ hb, const unsigned short* __restrict__ reps,
    const float* __restrict__ bias, float* __restrict__ out)
{
    __shared__ unsigned short As[2][4096];
    __shared__ unsigned short Bs[2][4096];

    const int mb = blockIdx.y;   // 0..31  batch block
    const int nb = blockIdx.x;   // 0..63  feature block
    const int t = threadIdx.x;
    const int wave = t >> 6, lane = t & 63;
    const int wm = (wave >> 1) * 64, wn = (wave & 1) * 64;
    const int quad = lane >> 4, l16 = lane & 15;

    const unsigned short* atile = hb   + ((long)mb << 15);   // mb*8*4096
    const unsigned short* btile = reps + ((long)nb << 15);

    f32x4 acc[4][4];
    #pragma unroll
    for (int i = 0; i < 4; ++i)
        #pragma unroll
        for (int j = 0; j < 4; ++j)
            acc[i][j] = (f32x4){0.f, 0.f, 0.f, 0.f};

    // prologue: stage step 0
    #pragma unroll
    for (int i = 0; i < 2; ++i) {
        const int o = wave * 1024 + i * 4096;
        gload16((const char*)atile + o + lane * 16, (char*)&As[0][0] + o);
        gload16((const char*)btile + o + lane * 16, (char*)&Bs[0][0] + o);
    }
    __syncthreads();

    int cur = 0;
    #pragma unroll 1
    for (int s = 0; s < 8; ++s) {
        if (s + 1 < 8) {
            #pragma unroll
            for (int i = 0; i < 2; ++i) {
                const int o = wave * 1024 + i * 4096;
                gload16((const char*)atile + ((long)(s + 1) << 13) + o + lane * 16,
                        (char*)&As[cur ^ 1][0] + o);
                gload16((const char*)btile + ((long)(s + 1) << 13) + o + lane * 16,
                        (char*)&Bs[cur ^ 1][0] + o);
            }
        }

        bf16x8 af[4], bfr[4];
        #pragma unroll
        for (int i = 0; i < 4; ++i)
            af[i] = *(const bf16x8*)&As[cur][quad * 1024 + (wm + i * 16 + l16) * 8];
        #pragma unroll
        for (int j = 0; j < 4; ++j)
            bfr[j] = *(const bf16x8*)&Bs[cur][quad * 1024 + (wn + j * 16 + l16) * 8];

        #pragma unroll
        for (int i = 0; i < 4; ++i)
            #pragma unroll
            for (int j = 0; j < 4; ++j)
                acc[i][j] = __builtin_amdgcn_mfma_f32_16x16x32_bf16(
                    af[i], bfr[j], acc[i][j], 0, 0, 0);

        __syncthreads();
        cur ^= 1;
    }

    #pragma unroll
    for (int i = 0; i < 4; ++i)
        #pragma unroll
        for (int j = 0; j < 4; ++j) {
            const int col = nb * 128 + wn + j * 16 + l16;
            const float bv = bias[col];
            #pragma unroll
            for (int r = 0; r < 4; ++r) {
                const int rowg = mb * 128 + wm + i * 16 + quad * 4 + r;
                out[(long)rowg * N_FEAT + col] = fmaxf(acc[i][j][r] + bv, 0.f);
            }
        }
}

// ---------------------------------------------------------------------------
extern "C" void kernel_launch(void* const* d_in, const int* in_sizes, int n_in,
                              void* d_out, int out_size, void* d_ws, size_t ws_size,
                              hipStream_t stream) {
    const float* x    = (const float*)d_in[0];
    const float* proj = (const float*)d_in[1];
    const float* rw   = (const float*)d_in[2];
    const float* rb   = (const float*)d_in[3];
    const float* cb   = (const float*)d_in[4];
    const float* bias = (const float*)d_in[5];
    float* out = (float*)d_out;

    char* ws = (char*)d_ws;
    unsigned short* reps_bf = (unsigned short*)ws;                 // 4 MB (packed gemm2-B tiles)
    unsigned short* repsT   = (unsigned short*)(ws + (4u << 20));  // 4 MB (packed gemm1-B tiles)
    unsigned short* hid_prt = (unsigned short*)(ws + (8u << 20));  // 32 MB (16 x 2 MB, packed)
    unsigned short* hid_bf  = (unsigned short*)(ws + (40u << 20)); // 2 MB (packed gemm2-A tiles)

    reps_kernel<<<N_FEAT / NT, 256, 0, stream>>>(proj, rw, rb, cb, reps_bf, repsT);
    gemm1_kernel<<<dim3(2, 32, KSPLIT), 256, 0, stream>>>(x, repsT, hid_prt);
    reduce_kernel<<<512, 256, 0, stream>>>(hid_prt, hid_bf);
    gemm2_kernel<<<dim3(64, 32), 256, 0, stream>>>(hid_bf, reps_bf, bias, out);
}

// Round 4
// 319.892 us; speedup vs baseline: 1.0536x; 1.0536x over previous
//
#include <hip/hip_runtime.h>
#include <hip/hip_bf16.h>

#define N_FEAT 8192
#define D_MODEL 256
#define HEADS 4
#define CELLS 32
#define BATCH 4096
#define HC 128          // HEADS*CELLS
#define NT 32           // n-rows per reps block
#define DC 64           // d-chunk
#define KSPLIT 8
#define KCH (N_FEAT / KSPLIT)   // 1024
#define NSTEPS (KCH / 32)       // 32

typedef __attribute__((ext_vector_type(8))) short bf16x8;
typedef __attribute__((ext_vector_type(4))) float f32x4;

__device__ __forceinline__ unsigned short f32_to_bf16(float f) {
    union { float f; unsigned u; } v; v.f = f;
    unsigned r = v.u + 0x7fffu + ((v.u >> 16) & 1u);
    return (unsigned short)(r >> 16);
}

__device__ __forceinline__ float bf16_to_f32(unsigned short h) {
    union { unsigned u; float f; } v; v.u = ((unsigned)h) << 16;
    return v.f;
}

// direct global->LDS DMA, 16B per lane; global src is PER-LANE, LDS dest is
// wave-uniform base (+ lane*16 added by HW)
__device__ __forceinline__ void gload16(const void* gsrc, void* ldst) {
    __builtin_amdgcn_global_load_lds(
        (const __attribute__((address_space(1))) unsigned int*)gsrc,
        (__attribute__((address_space(3))) unsigned int*)ldst, 16, 0, 0);
}

// ---------------------------------------------------------------------------
// Packed tile layouts (all intermediates are fragment-native):
//   repsT  : [n_blk(2)][k_step(256)][kq(4)][row(128)][8] bf16   (gemm1 B)
//   reps_bf: [n_blk(64)][ks2(8)][kq(4)][row(128)][8] bf16       (gemm2 B)
//   hb/hp  : [m_blk(32)][ks2(8)][kq(4)][row(128)][8] bf16       (gemm2 A)
// ---------------------------------------------------------------------------

// ---------------------------------------------------------------------------
// Stage 1 (fused): tropical scores -> top-2 -> sigmoid blend -> packed writes
// ---------------------------------------------------------------------------
__global__ __launch_bounds__(256) void reps_kernel(
    const float* __restrict__ proj, const float* __restrict__ rw,
    const float* __restrict__ rb, const float* __restrict__ cb,
    unsigned short* __restrict__ reps_bf, unsigned short* __restrict__ repsT)
{
    __shared__ float latS[NT][DC + 4];
    __shared__ float wS[HC][DC + 4];
    __shared__ float sc[NT][HC + 4];
    __shared__ float T[NT][257];
    __shared__ float gateS[NT][HEADS];
    __shared__ int   widxS[NT][HEADS], ridxS[NT][HEADS];

    const int t = threadIdx.x;
    const int nbase = blockIdx.x * NT;
    const int tx = t & 31, ty = t >> 5;
    const int hc0 = tx * 4, n0 = ty * 4;

    float acc[4][4];
    #pragma unroll
    for (int i = 0; i < 4; ++i)
        #pragma unroll
        for (int j = 0; j < 4; ++j)
            acc[i][j] = -3.4e38f;

    for (int dk = 0; dk < D_MODEL; dk += DC) {
        __syncthreads();
        {
            int f = t;
            #pragma unroll
            for (int i = 0; i < 2; ++i, f += 256) {
                const int row = f >> 4, c4 = f & 15;
                float4 v = *(const float4*)&proj[(long)(nbase + row) * D_MODEL + dk + c4 * 4];
                *(float4*)&latS[row][c4 * 4] = v;
            }
        }
        {
            int f = t;
            #pragma unroll
            for (int i = 0; i < 8; ++i, f += 256) {
                const int row = f >> 4, c4 = f & 15;
                float4 v = *(const float4*)&rw[(long)row * D_MODEL + dk + c4 * 4];
                *(float4*)&wS[row][c4 * 4] = v;
            }
        }
        __syncthreads();

        #pragma unroll 4
        for (int d = 0; d < DC; d += 4) {
            float4 la[4], wv[4];
            #pragma unroll
            for (int i = 0; i < 4; ++i) la[i] = *(const float4*)&latS[n0 + i][d];
            #pragma unroll
            for (int j = 0; j < 4; ++j) wv[j] = *(const float4*)&wS[hc0 + j][d];
            #pragma unroll
            for (int i = 0; i < 4; ++i)
                #pragma unroll
                for (int j = 0; j < 4; ++j) {
                    float m01 = fmaxf(la[i].x + wv[j].x, la[i].y + wv[j].y);
                    float m23 = fmaxf(la[i].z + wv[j].z, la[i].w + wv[j].w);
                    acc[i][j] = fmaxf(acc[i][j], fmaxf(m01, m23));
                }
        }
    }

    #pragma unroll
    for (int j = 0; j < 4; ++j) {
        const float rbv = rb[hc0 + j];
        #pragma unroll
        for (int i = 0; i < 4; ++i)
            sc[n0 + i][hc0 + j] = acc[i][j] + rbv;
    }
    __syncthreads();

    if (t < NT * HEADS) {
        const int n = t >> 2, h = t & 3;
        float v1 = -3.4e38f, v2 = -3.4e38f; int i1 = 0, i2 = 0;
        #pragma unroll
        for (int c = 0; c < CELLS; ++c) {
            float s = sc[n][h * CELLS + c];
            if (s > v1) { v2 = v1; i2 = i1; v1 = s; i1 = c; }
            else if (s > v2) { v2 = s; i2 = c; }
        }
        gateS[n][h] = 1.0f / (1.0f + __expf(-(v1 - v2)));
        widxS[n][h] = i1; ridxS[n][h] = i2;
    }
    __syncthreads();

    // blend; write reps_bf in gemm2-B packed layout; keep f32 row in T
    const long nblk2 = nbase >> 7;          // gemm2 n-block
    const int  rbase = nbase & 127;         // row128 base within that block
    #pragma unroll 4
    for (int r = 0; r < NT; ++r) {
        float val = proj[(long)(nbase + r) * D_MODEL + t];
        #pragma unroll
        for (int h = 0; h < HEADS; ++h) {
            const float g = gateS[r][h];
            const float wv = cb[(long)(h * CELLS + widxS[r][h]) * D_MODEL + t];
            const float rv = cb[(long)(h * CELLS + ridxS[r][h]) * D_MODEL + t];
            val += g * wv + (1.0f - g) * rv;   // CODE_SCALE = 1
        }
        // d = t: ks2 = t>>5, kq = (t>>3)&3, ko = t&7
        const long bidx = ((((nblk2 * 8 + (t >> 5)) * 4 + ((t >> 3) & 3)) * 128
                           + (rbase + r)) << 3) + (t & 7);
        reps_bf[bidx] = f32_to_bf16(val);
        T[r][t] = val;
    }
    __syncthreads();

    // pack repsT tiles for gemm1 B: this block covers one gemm1 k_step
    // thread t = d (0..255): n_blk = t>>7, row = t&127
    {
        const int ksA = nbase >> 5;     // gemm1 k-step index (global)
        const long tb = (((long)(t >> 7) * 256 + ksA) * 4);
        #pragma unroll
        for (int kq = 0; kq < 4; ++kq) {
            unsigned short tmp[8];
            #pragma unroll
            for (int ko = 0; ko < 8; ++ko)
                tmp[ko] = f32_to_bf16(T[kq * 8 + ko][t]);
            *(uint4*)&repsT[((tb + kq) * 128 + (t & 127)) << 3] = *(const uint4*)tmp;
        }
    }
}

// ---------------------------------------------------------------------------
// Stage 2: hidden_part[ks] = x[:, ks-chunk] @ reps[ks-chunk, :]  (bf16 out)
// 128x128 tile, 4 waves, 4x4 16x16x32 MFMA, K-split x8 (32 steps/block).
// DEPTH-3 counted-vmcnt pipeline (T3+T4): both operands DMA'd via
// global_load_lds into a 3-slot circular LDS buffer; raw s_barrier +
// s_waitcnt vmcnt(12) keeps 2 stages (12 loads) in flight ACROSS barriers.
// A staged as raw f32 in [kq][row][8f] packed layout, cvt at fragment read.
// ---------------------------------------------------------------------------
__global__ __launch_bounds__(256) void gemm1_kernel(
    const float* __restrict__ x, const unsigned short* __restrict__ repsT,
    unsigned short* __restrict__ hidden_part)
{
    __shared__ float          As[3][4096];   // [kq(4)][row(128)][8 f32] 16KB/slot
    __shared__ unsigned short Bs[3][4096];   // [kq(4)][row(128)][8 bf16] 8KB/slot

    const int m0 = blockIdx.y * 128;
    const int nb = blockIdx.x;               // 0..1  (d-block of 128)
    const int ks = blockIdx.z;
    const int t = threadIdx.x;
    const int wave = t >> 6, lane = t & 63;
    const int wm = (wave >> 1) * 64, wn = (wave & 1) * 64;
    const int quad = lane >> 4, l16 = lane & 15;
    const int kbeg = ks * KCH;
    const int gs0 = kbeg >> 5;               // first global k-step index

    // A DMA geometry: chunk c = wave*4+i; kq = wave, row = i*32 + lane>>1,
    // half = lane&1  ->  LDS float idx = c*256 + lane*4 = kq*1024 + row*8 + half*4
    const int arow_half = lane >> 1, ahf = lane & 1;

    f32x4 acc[4][4];
    #pragma unroll
    for (int i = 0; i < 4; ++i)
        #pragma unroll
        for (int j = 0; j < 4; ++j)
            acc[i][j] = (f32x4){0.f, 0.f, 0.f, 0.f};

    // stage issuer: 6 gload16 per wave (2 for B, 4 for A)
    #define ISSUE_STAGE(s_, b_)                                                   \
    {                                                                             \
        const char* bsrc = (const char*)repsT + (((long)nb * 256 + gs0 + (s_)) << 13); \
        char* bdst = (char*)&Bs[(b_)][0];                                         \
        gload16(bsrc + wave * 1024 + lane * 16,        bdst + wave * 1024);       \
        gload16(bsrc + wave * 1024 + 4096 + lane * 16, bdst + wave * 1024 + 4096);\
        const long kg = kbeg + (long)(s_) * 32;                                   \
        _Pragma("unroll")                                                         \
        for (int i_ = 0; i_ < 4; ++i_) {                                          \
            const int c_ = wave * 4 + i_;                                         \
            gload16(&x[(long)(m0 + i_ * 32 + arow_half) * N_FEAT + kg + wave * 8 + ahf * 4], \
                    (char*)&As[(b_)][0] + c_ * 1024);                             \
        }                                                                         \
    }

    // prologue: fill the 3-deep pipe (18 loads outstanding per wave)
    ISSUE_STAGE(0, 0);
    ISSUE_STAGE(1, 1);
    ISSUE_STAGE(2, 2);

    int b = 0;
    #pragma unroll 1
    for (int s = 0; s < NSTEPS; ++s) {
        // wait for MY stage-s loads only (2 later stages stay in flight)
        if (s < NSTEPS - 2)       { asm volatile("s_waitcnt vmcnt(12)" ::: "memory"); }
        else if (s == NSTEPS - 2) { asm volatile("s_waitcnt vmcnt(6)"  ::: "memory"); }
        else                      { asm volatile("s_waitcnt vmcnt(0)"  ::: "memory"); }
        __builtin_amdgcn_s_barrier();        // everyone's stage-s data in LDS

        // fragments from slot b (conflict-free-ish contiguous reads)
        bf16x8 af[4], bfr[4];
        #pragma unroll
        for (int i = 0; i < 4; ++i) {
            const float4 a0 = *(const float4*)&As[b][quad * 1024 + (wm + i * 16 + l16) * 8];
            const float4 a1 = *(const float4*)&As[b][quad * 1024 + (wm + i * 16 + l16) * 8 + 4];
            union { unsigned short u[8]; bf16x8 v; } c;
            c.u[0] = f32_to_bf16(a0.x); c.u[1] = f32_to_bf16(a0.y);
            c.u[2] = f32_to_bf16(a0.z); c.u[3] = f32_to_bf16(a0.w);
            c.u[4] = f32_to_bf16(a1.x); c.u[5] = f32_to_bf16(a1.y);
            c.u[6] = f32_to_bf16(a1.z); c.u[7] = f32_to_bf16(a1.w);
            af[i] = c.v;
        }
        #pragma unroll
        for (int j = 0; j < 4; ++j)
            bfr[j] = *(const bf16x8*)&Bs[b][quad * 1024 + (wn + j * 16 + l16) * 8];

        // all my LDS reads done; fence, then barrier so slot b is reusable
        asm volatile("s_waitcnt lgkmcnt(0)" ::: "memory");
        __builtin_amdgcn_sched_barrier(0);
        __builtin_amdgcn_s_barrier();

        // refill slot b with stage s+3 (in flight across the next 2 steps)
        if (s + 3 < NSTEPS) ISSUE_STAGE(s + 3, b);

        #pragma unroll
        for (int i = 0; i < 4; ++i)
            #pragma unroll
            for (int j = 0; j < 4; ++j)
                acc[i][j] = __builtin_amdgcn_mfma_f32_16x16x32_bf16(
                    af[i], bfr[j], acc[i][j], 0, 0, 0);

        b = (b == 2) ? 0 : b + 1;
    }
    #undef ISSUE_STAGE

    // epilogue: write hp stripe in gemm2-A packed layout
    unsigned short* hp = hidden_part + (long)ks * (BATCH * D_MODEL);
    #pragma unroll
    for (int i = 0; i < 4; ++i)
        #pragma unroll
        for (int j = 0; j < 4; ++j) {
            const int d0 = nb * 128 + wn + j * 16;        // multiple of 16
            const int ks2 = d0 >> 5;                      // fixed across l16
            const int kq2 = ((d0 + l16) >> 3) & 3;
            const int ko  = l16 & 7;
            const long cb = ((long)blockIdx.y * 8 + ks2) * 4 + kq2;
            #pragma unroll
            for (int r = 0; r < 4; ++r) {
                const int row128 = wm + i * 16 + quad * 4 + r;
                hp[((cb * 128 + row128) << 3) + ko] = f32_to_bf16(acc[i][j][r]);
            }
        }
}

// ---------------------------------------------------------------------------
// Stage 2b: hb = bf16( sum of 8 bf16 K-split partials ) — layout-agnostic
// ---------------------------------------------------------------------------
__global__ __launch_bounds__(256) void reduce_kernel(
    const unsigned short* __restrict__ hp, unsigned short* __restrict__ hb)
{
    const int id = blockIdx.x * 256 + threadIdx.x;   // over 131072 uint4 (8 bf16)
    const int S = BATCH * D_MODEL / 8;
    const uint4* p = (const uint4*)hp;
    float s[8] = {0.f, 0.f, 0.f, 0.f, 0.f, 0.f, 0.f, 0.f};
    #pragma unroll
    for (int k = 0; k < KSPLIT; ++k) {
        uint4 v = p[(long)k * S + id];
        unsigned short e[8];
        *(uint4*)e = v;
        #pragma unroll
        for (int j = 0; j < 8; ++j) s[j] += bf16_to_f32(e[j]);
    }
    unsigned short o[8];
    #pragma unroll
    for (int j = 0; j < 8; ++j) o[j] = f32_to_bf16(s[j]);
    ((uint4*)hb)[id] = *(const uint4*)o;
}

// ---------------------------------------------------------------------------
// Stage 3: out = relu(hidden @ reps^T + bias)   M=4096 N=8192 K=256
// Both operands DMA'd linearly from packed tiles; conflict-free reads.
// ---------------------------------------------------------------------------
__global__ __launch_bounds__(256) void gemm2_kernel(
    const unsigned short* __restrict__ hb, const unsigned short* __restrict__ reps,
    const float* __restrict__ bias, float* __restrict__ out)
{
    __shared__ unsigned short As[2][4096];
    __shared__ unsigned short Bs[2][4096];

    const int mb = blockIdx.y;   // 0..31  batch block
    const int nb = blockIdx.x;   // 0..63  feature block
    const int t = threadIdx.x;
    const int wave = t >> 6, lane = t & 63;
    const int wm = (wave >> 1) * 64, wn = (wave & 1) * 64;
    const int quad = lane >> 4, l16 = lane & 15;

    const unsigned short* atile = hb   + ((long)mb << 15);   // mb*8*4096
    const unsigned short* btile = reps + ((long)nb << 15);

    f32x4 acc[4][4];
    #pragma unroll
    for (int i = 0; i < 4; ++i)
        #pragma unroll
        for (int j = 0; j < 4; ++j)
            acc[i][j] = (f32x4){0.f, 0.f, 0.f, 0.f};

    // prologue: stage step 0
    #pragma unroll
    for (int i = 0; i < 2; ++i) {
        const int o = wave * 1024 + i * 4096;
        gload16((const char*)atile + o + lane * 16, (char*)&As[0][0] + o);
        gload16((const char*)btile + o + lane * 16, (char*)&Bs[0][0] + o);
    }
    __syncthreads();

    int cur = 0;
    #pragma unroll 1
    for (int s = 0; s < 8; ++s) {
        if (s + 1 < 8) {
            #pragma unroll
            for (int i = 0; i < 2; ++i) {
                const int o = wave * 1024 + i * 4096;
                gload16((const char*)atile + ((long)(s + 1) << 13) + o + lane * 16,
                        (char*)&As[cur ^ 1][0] + o);
                gload16((const char*)btile + ((long)(s + 1) << 13) + o + lane * 16,
                        (char*)&Bs[cur ^ 1][0] + o);
            }
        }

        bf16x8 af[4], bfr[4];
        #pragma unroll
        for (int i = 0; i < 4; ++i)
            af[i] = *(const bf16x8*)&As[cur][quad * 1024 + (wm + i * 16 + l16) * 8];
        #pragma unroll
        for (int j = 0; j < 4; ++j)
            bfr[j] = *(const bf16x8*)&Bs[cur][quad * 1024 + (wn + j * 16 + l16) * 8];

        #pragma unroll
        for (int i = 0; i < 4; ++i)
            #pragma unroll
            for (int j = 0; j < 4; ++j)
                acc[i][j] = __builtin_amdgcn_mfma_f32_16x16x32_bf16(
                    af[i], bfr[j], acc[i][j], 0, 0, 0);

        __syncthreads();
        cur ^= 1;
    }

    #pragma unroll
    for (int i = 0; i < 4; ++i)
        #pragma unroll
        for (int j = 0; j < 4; ++j) {
            const int col = nb * 128 + wn + j * 16 + l16;
            const float bv = bias[col];
            #pragma unroll
            for (int r = 0; r < 4; ++r) {
                const int rowg = mb * 128 + wm + i * 16 + quad * 4 + r;
                out[(long)rowg * N_FEAT + col] = fmaxf(acc[i][j][r] + bv, 0.f);
            }
        }
}

// ---------------------------------------------------------------------------
extern "C" void kernel_launch(void* const* d_in, const int* in_sizes, int n_in,
                              void* d_out, int out_size, void* d_ws, size_t ws_size,
                              hipStream_t stream) {
    const float* x    = (const float*)d_in[0];
    const float* proj = (const float*)d_in[1];
    const float* rw   = (const float*)d_in[2];
    const float* rb   = (const float*)d_in[3];
    const float* cb   = (const float*)d_in[4];
    const float* bias = (const float*)d_in[5];
    float* out = (float*)d_out;

    char* ws = (char*)d_ws;
    unsigned short* reps_bf = (unsigned short*)ws;                 // 4 MB (packed gemm2-B tiles)
    unsigned short* repsT   = (unsigned short*)(ws + (4u << 20));  // 4 MB (packed gemm1-B tiles)
    unsigned short* hid_prt = (unsigned short*)(ws + (8u << 20));  // 16 MB (8 x 2 MB, packed)
    unsigned short* hid_bf  = (unsigned short*)(ws + (24u << 20)); // 2 MB (packed gemm2-A tiles)

    reps_kernel<<<N_FEAT / NT, 256, 0, stream>>>(proj, rw, rb, cb, reps_bf, repsT);
    gemm1_kernel<<<dim3(2, 32, KSPLIT), 256, 0, stream>>>(x, repsT, hid_prt);
    reduce_kernel<<<512, 256, 0, stream>>>(hid_prt, hid_bf);
    gemm2_kernel<<<dim3(64, 32), 256, 0, stream>>>(hid_bf, reps_bf, bias, out);
}